// Round 3
// baseline (423.168 us; speedup 1.0000x reference)
//
#include <hip/hip_runtime.h>
#include <hip/hip_bf16.h>

typedef _Float16 f16;
typedef __attribute__((ext_vector_type(8))) _Float16 half8;
typedef __attribute__((ext_vector_type(4))) float f32x4;

#define BM 256
#define BN 256
#define BK 64

// async global->LDS, 16B per lane; LDS dest is wave-uniform base + lane*16
__device__ __forceinline__ void gl2lds16(const f16* g, const f16* l) {
    __builtin_amdgcn_global_load_lds(
        (const __attribute__((address_space(1))) unsigned int*)g,
        (__attribute__((address_space(3))) unsigned int*)l, 16, 0, 0);
}

template<int V>
__device__ __forceinline__ void waitv() {
    asm volatile("s_waitcnt vmcnt(%0)" :: "i"(V) : "memory");
}

#define MFMA(d, a, b) d = __builtin_amdgcn_mfma_f32_16x16x32_f16(a, b, d, 0, 0, 0)

// ---------------------------------------------------------------------------
// Dual elementwise cast fp32 -> fp16, 8 elems/thread (q and k in one launch)
// ---------------------------------------------------------------------------
__global__ __launch_bounds__(256)
void cast2_f16(const float* __restrict__ in0, f16* __restrict__ out0,
               const float* __restrict__ in1, f16* __restrict__ out1, long long n) {
    const float* in = blockIdx.y ? in1 : in0;
    f16* out       = blockIdx.y ? out1 : out0;
    long long i = ((long long)blockIdx.x * 256 + threadIdx.x) * 8;
    if (i >= n) return;
    float4 a = *(const float4*)&in[i];
    float4 b = *(const float4*)&in[i + 4];
    union { f16 h[8]; uint4 q; } H;
    H.h[0] = (f16)a.x; H.h[1] = (f16)a.y; H.h[2] = (f16)a.z; H.h[3] = (f16)a.w;
    H.h[4] = (f16)b.x; H.h[5] = (f16)b.y; H.h[6] = (f16)b.z; H.h[7] = (f16)b.w;
    *(uint4*)&out[i] = H.q;
}

// ---------------------------------------------------------------------------
// Transpose + cast: fp32 [R][C] -> fp16 [C][R], 64x64 tiles, half8 stores
// ---------------------------------------------------------------------------
__global__ __launch_bounds__(256)
void transpose64_f16(const float* __restrict__ in, f16* __restrict__ out,
                     int R, int C, long long in_stride, long long out_stride) {
    const int b = blockIdx.z;
    in += (size_t)b * in_stride;
    out += (size_t)b * out_stride;

    __shared__ float tile[64][68];
    const int c0 = blockIdx.x * 64, r0 = blockIdx.y * 64;
    const int t = threadIdx.x;

    const int lr = t >> 4, lc4 = (t & 15) * 4;
#pragma unroll
    for (int p = 0; p < 4; p++) {
        float4 v = *(const float4*)&in[(size_t)(r0 + p * 16 + lr) * C + c0 + lc4];
        *(float4*)&tile[p * 16 + lr][lc4] = v;
    }
    __syncthreads();

    const int oc_ = t >> 3, rr = (t & 7) * 8;
#pragma unroll
    for (int p = 0; p < 2; p++) {
        const int oc = p * 32 + oc_;
        union { f16 h[8]; uint4 q; } H;
#pragma unroll
        for (int i = 0; i < 8; i++) H.h[i] = (f16)tile[rr + i][oc];
        *(uint4*)&out[(size_t)(c0 + oc) * R + r0 + rr] = H.q;
    }
}

// ---------------------------------------------------------------------------
// B^T-layout fp16 GEMM, 256x256 tile, BK=64, 8 waves, 4-phase dbuf schedule.
// Wait discipline: single vmcnt(0)+barrier at iteration top (tile t's loads
// were issued by P1 of iter t-1 -> 2-3 phases of slack). Stages front-loaded
// to P0 (A) / P1 (B). One barrier per iter (top barrier subsumes the
// overwrite guard since stages are issued after it).
//   EPI: 0 = fp32 store; 2 = fp16 store.  XR: 1 = batch-XCD remap (grid 4,4,16)
// ---------------------------------------------------------------------------
template<int EPI, int XR>
__global__ __launch_bounds__(512, 2)
void gemm256(const f16* __restrict__ A_, const f16* __restrict__ B_,
             float* __restrict__ Cf, f16* __restrict__ Ch,
             int M, int N, int K,
             long long batchA, long long batchB, long long batchC) {
    int bx, by, bz;
    if constexpr (XR == 1) {
        const int d = blockIdx.z * 16 + blockIdx.y * 4 + blockIdx.x;
        const int xcd = d & 7, j = d >> 3, i2 = j & 15;
        bz = xcd + 8 * (j >> 4); by = i2 >> 2; bx = i2 & 3;
    } else {
        bx = blockIdx.x; by = blockIdx.y; bz = blockIdx.z;
    }
    const int b = bz;
    const int m0 = by * BM;
    const int n0 = bx * BN;
    const int t = threadIdx.x;
    const int lane = t & 63, wv = t >> 6;
    const int wr = wv >> 2;
    const int wc = wv & 3;

    const f16* A = A_ + (size_t)b * batchA;
    const f16* B = B_ + (size_t)b * batchB;

    __shared__ alignas(16) f16 sA[2][2][128][64];
    __shared__ alignas(16) f16 sB[2][2][128][64];

    const int srow  = wv * 16 + (lane >> 3);
    const int gslot = (lane & 7) ^ (lane >> 3);

    const f16* gAl  = A + (size_t)(m0 + srow) * K + gslot * 8;
    const f16* gAl8 = gAl + (size_t)8 * K;
    const f16* gAh  = gAl + (size_t)128 * K;
    const f16* gAh8 = gAl8 + (size_t)128 * K;
    const f16* gBl  = B + (size_t)(n0 + srow) * K + gslot * 8;
    const f16* gBl8 = gBl + (size_t)8 * K;
    const f16* gBh  = gBl + (size_t)128 * K;
    const f16* gBh8 = gBl8 + (size_t)128 * K;

    f32x4 acc[8][4];
#pragma unroll
    for (int i = 0; i < 8; i++)
#pragma unroll
        for (int j = 0; j < 4; j++)
#pragma unroll
            for (int r = 0; r < 4; r++) acc[i][j][r] = 0.0f;

    gl2lds16(gAl,  &sA[0][0][wv * 16][0]); gl2lds16(gAl8, &sA[0][0][wv * 16 + 8][0]);
    gl2lds16(gAh,  &sA[0][1][wv * 16][0]); gl2lds16(gAh8, &sA[0][1][wv * 16 + 8][0]);
    gl2lds16(gBl,  &sB[0][0][wv * 16][0]); gl2lds16(gBl8, &sB[0][0][wv * 16 + 8][0]);
    gl2lds16(gBh,  &sB[0][1][wv * 16][0]); gl2lds16(gBh8, &sB[0][1][wv * 16 + 8][0]);

    const int fr  = lane & 15;
    const int fq4 = lane >> 4;
    const int NT  = K / BK;

    half8 af[4][2], bA[2][2], bB[2][2];

    for (int tt = 0; tt < NT; ++tt) {
        const int c = tt & 1, cn = c ^ 1;
        const size_t kg = (size_t)(tt + 1) * BK;
        const bool nx = (tt + 1 < NT);

        const f16* pa = &sA[c][wr][fr][0];
        const f16* pb = &sB[c][wc >> 1][(wc & 1) * 64 + fr][0];
        const int cs0 = ((0 + fq4) ^ (fr & 7)) * 8;
        const int cs1 = ((4 + fq4) ^ (fr & 7)) * 8;

        // ---- top: tile t fully resident; also guards buffer overwrite
        asm volatile("s_waitcnt vmcnt(0)\n\ts_barrier" ::: "memory");

        // ---- P0: stage next A; read lo-frags + all B-frags; MFMA quad 00
        if (nx) {
            gl2lds16(gAl + kg,  &sA[cn][0][wv * 16][0]);
            gl2lds16(gAl8 + kg, &sA[cn][0][wv * 16 + 8][0]);
            gl2lds16(gAh + kg,  &sA[cn][1][wv * 16][0]);
            gl2lds16(gAh8 + kg, &sA[cn][1][wv * 16 + 8][0]);
        }
#pragma unroll
        for (int mi = 0; mi < 4; mi++) {
            af[mi][0] = *(const half8*)(pa + mi * 1024 + cs0);
            af[mi][1] = *(const half8*)(pa + mi * 1024 + cs1);
        }
#pragma unroll
        for (int ni = 0; ni < 2; ni++) {
            bA[ni][0] = *(const half8*)(pb + ni * 1024 + cs0);
            bA[ni][1] = *(const half8*)(pb + ni * 1024 + cs1);
        }
#pragma unroll
        for (int ni = 0; ni < 2; ni++) {
            bB[ni][0] = *(const half8*)(pb + (2 + ni) * 1024 + cs0);
            bB[ni][1] = *(const half8*)(pb + (2 + ni) * 1024 + cs1);
        }
        __builtin_amdgcn_s_setprio(1);
#pragma unroll
        for (int mi = 0; mi < 4; mi++)
#pragma unroll
            for (int ni = 0; ni < 2; ni++) {
                MFMA(acc[mi][ni], af[mi][0], bA[ni][0]);
                MFMA(acc[mi][ni], af[mi][1], bA[ni][1]);
            }
        __builtin_amdgcn_s_setprio(0);

        // ---- P1: stage next B; MFMA quad 01
        if (nx) {
            gl2lds16(gBl + kg,  &sB[cn][0][wv * 16][0]);
            gl2lds16(gBl8 + kg, &sB[cn][0][wv * 16 + 8][0]);
            gl2lds16(gBh + kg,  &sB[cn][1][wv * 16][0]);
            gl2lds16(gBh8 + kg, &sB[cn][1][wv * 16 + 8][0]);
        }
        __builtin_amdgcn_s_setprio(1);
#pragma unroll
        for (int mi = 0; mi < 4; mi++)
#pragma unroll
            for (int ni = 0; ni < 2; ni++) {
                MFMA(acc[mi][2 + ni], af[mi][0], bB[ni][0]);
                MFMA(acc[mi][2 + ni], af[mi][1], bB[ni][1]);
            }
        __builtin_amdgcn_s_setprio(0);

        // ---- P2: read af-hi; MFMA quad 11
#pragma unroll
        for (int mi = 0; mi < 4; mi++) {
            af[mi][0] = *(const half8*)(pa + (64 + mi * 16) * 64 + cs0);
            af[mi][1] = *(const half8*)(pa + (64 + mi * 16) * 64 + cs1);
        }
        __builtin_amdgcn_s_setprio(1);
#pragma unroll
        for (int mi = 0; mi < 4; mi++)
#pragma unroll
            for (int ni = 0; ni < 2; ni++) {
                MFMA(acc[4 + mi][2 + ni], af[mi][0], bB[ni][0]);
                MFMA(acc[4 + mi][2 + ni], af[mi][1], bB[ni][1]);
            }
        __builtin_amdgcn_s_setprio(0);

        // ---- P3: MFMA quad 10
        __builtin_amdgcn_s_setprio(1);
#pragma unroll
        for (int mi = 0; mi < 4; mi++)
#pragma unroll
            for (int ni = 0; ni < 2; ni++) {
                MFMA(acc[4 + mi][ni], af[mi][0], bA[ni][0]);
                MFMA(acc[4 + mi][ni], af[mi][1], bA[ni][1]);
            }
        __builtin_amdgcn_s_setprio(0);
    }

    // ---- epilogue ----
    const int q4 = (lane >> 4) * 4;
#pragma unroll
    for (int mi = 0; mi < 8; mi++)
#pragma unroll
        for (int ni = 0; ni < 4; ni++) {
            const int col = n0 + wc * 64 + ni * 16 + fr;
#pragma unroll
            for (int r = 0; r < 4; r++) {
                const int row = m0 + wr * 128 + mi * 16 + q4 + r;
                const size_t idx = (size_t)b * batchC + (size_t)row * N + col;
                float v = acc[mi][ni][r];
                if constexpr (EPI == 0) Cf[idx] = v;
                else                    Ch[idx] = (f16)v;
            }
        }
}

// ---------------------------------------------------------------------------
// Fused GEMM2 + mask + row-softmax. Block = 64 rows x full 1024 cols.
// KEY: B staging is WAVE-LOCAL (wave wv stages and reads exactly rows
// wv*128..+127) -> no cross-wave sync for B. 4-phase K-loop with per-phase
// counted vmcnt; each wait targets loads issued a FULL iteration earlier:
//   issue order/iter: P0:[B0,B1,A] P1:[B2,B3] P2:[B4,B5] P3:[B6,B7]  (9)
//   steady waits:  P0 vmcnt(6) (retires B0,B1,A of tile t), P1-P3 vmcnt(7)
//   last iter:     P0 6, P1 4, P2 2, P3 0
// ONE barrier per iter (P0, for cross-wave A visibility).
// Swizzle: LDS[r][s] = G[r][s ^ swz(r)], swz(r)=(r&3)^((r>>2)&3)  (<=2-way).
// ---------------------------------------------------------------------------
__global__ __launch_bounds__(512, 2)
void gemm_softmax(const f16* __restrict__ A_, const f16* __restrict__ B_,
                  const float* __restrict__ mask,
                  float* __restrict__ score, f16* __restrict__ sc,
                  int N, int K, long long MAT) {
    // batch-XCD remap: 2 batches per XCD -> 2x2MB K-panels fit 4MB L2
    const int d = blockIdx.z * 16 + blockIdx.y;
    const int xcd = d & 7, j = d >> 3;
    const int b = xcd + 8 * (j >> 4);
    const int m0 = (j & 15) * 64;

    const int t = threadIdx.x;
    const int lane = t & 63, wv = t >> 6;
    const int fr = lane & 15, fq4 = lane >> 4;

    const f16* A = A_ + (size_t)b * MAT;   // qw  [1024][1024]
    const f16* B = B_ + (size_t)b * MAT;   // keys[1024][1024] (B^T layout)

    __shared__ alignas(16) f16 sA2[2][64][32];    // 8 KB
    __shared__ alignas(16) f16 sB2[2][1024][32];  // 128 KB
    __shared__ float sRed[8][64];
    __shared__ float sRed2[64];

    // write-side source slots for the swizzle
    const int gslB = ((lane & 3) ^ ((lane >> 2) & 3) ^ (lane >> 4)) & 3;
    const int gslA = ((lane & 3) ^ ((lane >> 2) & 3) ^ ((wv * 2 + (lane >> 4)) & 3)) & 3;
    const f16* gB = B + (size_t)(wv * 128 + (lane >> 2)) * K + gslB * 8;
    const f16* gA = A + (size_t)(m0 + wv * 8 + (lane >> 2)) * K + gslA * 8; // lanes<32

#define STB(cn_, i_, kg_) gl2lds16(gB + (size_t)(i_) * 16 * K + (kg_), &sB2[cn_][wv * 128 + (i_) * 16][0])
#define STA(cn_, kg_)     if (lane < 32) gl2lds16(gA + (kg_), &sA2[cn_][wv * 8][0])

    f32x4 acc[4][8];
#pragma unroll
    for (int mi = 0; mi < 4; mi++)
#pragma unroll
        for (int ni = 0; ni < 8; ni++)
#pragma unroll
            for (int r = 0; r < 4; r++) acc[mi][ni][r] = 0.0f;

    // prologue: tile 0, issue order B0,B1,A,B2..B7
    STB(0, 0, 0); STB(0, 1, 0); STA(0, 0);
#pragma unroll
    for (int i = 2; i < 8; i++) STB(0, i, 0);

    const int NT = K / 32;
    const int sl = ((fq4 ^ (fr & 3) ^ (fr >> 2)) & 3) * 8;  // read slot (k-quarter fq4)
    half8 afr[4], bfr[8];

    for (int tt = 0; tt < NT; ++tt) {
        const int c = tt & 1, cn = c ^ 1;
        const size_t kg = (size_t)(tt + 1) * 32;
        const bool nx = (tt + 1 < NT);

        // ---- P0: wait B0,B1,A of tile t; barrier (A visibility); stage; mfma ni 0,1
        waitv<6>();
        asm volatile("s_barrier" ::: "memory");
        if (nx) { STB(cn, 0, kg); STB(cn, 1, kg); STA(cn, kg); }
#pragma unroll
        for (int mi = 0; mi < 4; mi++)
            afr[mi] = *(const half8*)&sA2[c][mi * 16 + fr][sl];
        bfr[0] = *(const half8*)&sB2[c][wv * 128 + 0 * 16 + fr][sl];
        bfr[1] = *(const half8*)&sB2[c][wv * 128 + 1 * 16 + fr][sl];
        __builtin_amdgcn_s_setprio(1);
#pragma unroll
        for (int mi = 0; mi < 4; mi++) { MFMA(acc[mi][0], afr[mi], bfr[0]); MFMA(acc[mi][1], afr[mi], bfr[1]); }
        __builtin_amdgcn_s_setprio(0);

        // ---- P1
        if (nx) waitv<7>(); else waitv<4>();
        if (nx) { STB(cn, 2, kg); STB(cn, 3, kg); }
        bfr[2] = *(const half8*)&sB2[c][wv * 128 + 2 * 16 + fr][sl];
        bfr[3] = *(const half8*)&sB2[c][wv * 128 + 3 * 16 + fr][sl];
        __builtin_amdgcn_s_setprio(1);
#pragma unroll
        for (int mi = 0; mi < 4; mi++) { MFMA(acc[mi][2], afr[mi], bfr[2]); MFMA(acc[mi][3], afr[mi], bfr[3]); }
        __builtin_amdgcn_s_setprio(0);

        // ---- P2
        if (nx) waitv<7>(); else waitv<2>();
        if (nx) { STB(cn, 4, kg); STB(cn, 5, kg); }
        bfr[4] = *(const half8*)&sB2[c][wv * 128 + 4 * 16 + fr][sl];
        bfr[5] = *(const half8*)&sB2[c][wv * 128 + 5 * 16 + fr][sl];
        __builtin_amdgcn_s_setprio(1);
#pragma unroll
        for (int mi = 0; mi < 4; mi++) { MFMA(acc[mi][4], afr[mi], bfr[4]); MFMA(acc[mi][5], afr[mi], bfr[5]); }
        __builtin_amdgcn_s_setprio(0);

        // ---- P3
        if (nx) waitv<7>(); else waitv<0>();
        if (nx) { STB(cn, 6, kg); STB(cn, 7, kg); }
        bfr[6] = *(const half8*)&sB2[c][wv * 128 + 6 * 16 + fr][sl];
        bfr[7] = *(const half8*)&sB2[c][wv * 128 + 7 * 16 + fr][sl];
        __builtin_amdgcn_s_setprio(1);
#pragma unroll
        for (int mi = 0; mi < 4; mi++) { MFMA(acc[mi][6], afr[mi], bfr[6]); MFMA(acc[mi][7], afr[mi], bfr[7]); }
        __builtin_amdgcn_s_setprio(0);
    }
#undef STB
#undef STA

    // ---- epilogue: + mask, row softmax over the full 1024 cols ----
    const int q4 = (lane >> 4) * 4;

    float mv[8];
#pragma unroll
    for (int ni = 0; ni < 8; ni++)
        mv[ni] = mask[(size_t)b * N + wv * 128 + ni * 16 + fr];
#pragma unroll
    for (int mi = 0; mi < 4; mi++)
#pragma unroll
        for (int ni = 0; ni < 8; ni++)
#pragma unroll
            for (int r = 0; r < 4; r++) acc[mi][ni][r] += mv[ni];

    float pm[4][4];
#pragma unroll
    for (int mi = 0; mi < 4; mi++)
#pragma unroll
        for (int r = 0; r < 4; r++) {
            float x = acc[mi][0][r];
#pragma unroll
            for (int ni = 1; ni < 8; ni++) x = fmaxf(x, acc[mi][ni][r]);
            pm[mi][r] = x;
        }
#pragma unroll
    for (int o = 1; o < 16; o <<= 1)
#pragma unroll
        for (int mi = 0; mi < 4; mi++)
#pragma unroll
            for (int r = 0; r < 4; r++)
                pm[mi][r] = fmaxf(pm[mi][r], __shfl_xor(pm[mi][r], o));

    if (fr == 0)
#pragma unroll
        for (int mi = 0; mi < 4; mi++)
#pragma unroll
            for (int r = 0; r < 4; r++)
                sRed[wv][mi * 16 + q4 + r] = pm[mi][r];
    __syncthreads();
    if (t < 64) {
        float x = sRed[0][t];
#pragma unroll
        for (int w = 1; w < 8; w++) x = fmaxf(x, sRed[w][t]);
        sRed2[t] = x;
    }
    __syncthreads();

    float m_[4][4];
#pragma unroll
    for (int mi = 0; mi < 4; mi++)
#pragma unroll
        for (int r = 0; r < 4; r++) m_[mi][r] = sRed2[mi * 16 + q4 + r];

    float ps[4][4];
#pragma unroll
    for (int mi = 0; mi < 4; mi++)
#pragma unroll
        for (int r = 0; r < 4; r++) ps[mi][r] = 0.0f;
#pragma unroll
    for (int mi = 0; mi < 4; mi++)
#pragma unroll
        for (int ni = 0; ni < 8; ni++)
#pragma unroll
            for (int r = 0; r < 4; r++) {
                float e = __expf(acc[mi][ni][r] - m_[mi][r]);
                acc[mi][ni][r] = e;
                ps[mi][r] += e;
            }
#pragma unroll
    for (int o = 1; o < 16; o <<= 1)
#pragma unroll
        for (int mi = 0; mi < 4; mi++)
#pragma unroll
            for (int r = 0; r < 4; r++)
                ps[mi][r] += __shfl_xor(ps[mi][r], o);

    if (fr == 0)
#pragma unroll
        for (int mi = 0; mi < 4; mi++)
#pragma unroll
            for (int r = 0; r < 4; r++)
                sRed[wv][mi * 16 + q4 + r] = ps[mi][r];
    __syncthreads();
    if (t < 64) {
        float x = sRed[0][t];
#pragma unroll
        for (int w = 1; w < 8; w++) x += sRed[w][t];
        sRed2[t] = x;
    }
    __syncthreads();

    float inv[4][4];
#pragma unroll
    for (int mi = 0; mi < 4; mi++)
#pragma unroll
        for (int r = 0; r < 4; r++) inv[mi][r] = 1.0f / sRed2[mi * 16 + q4 + r];

#pragma unroll
    for (int mi = 0; mi < 4; mi++)
#pragma unroll
        for (int ni = 0; ni < 8; ni++) {
            const int col = wv * 128 + ni * 16 + fr;
#pragma unroll
            for (int r = 0; r < 4; r++) {
                const int row = m0 + mi * 16 + q4 + r;
                const size_t idx = (size_t)b * MAT + (size_t)row * N + col;
                float v = acc[mi][ni][r] * inv[mi][r];
                score[idx] = v;
                sc[idx] = (f16)v;
            }
        }
}

// ---------------------------------------------------------------------------
extern "C" void kernel_launch(void* const* d_in, const int* in_sizes, int n_in,
                              void* d_out, int out_size, void* d_ws, size_t ws_size,
                              hipStream_t stream) {
    const int B = 16, T = 1024, D = 1024;
    const long long MAT = (long long)T * D;      // 1M elems
    const long long BT = (long long)B * MAT;     // 16M elems

    const float* query  = (const float*)d_in[0];
    const float* keys   = (const float*)d_in[1];
    const float* values = (const float*)d_in[2];
    const float* W      = (const float*)d_in[3];
    const float* mask   = (const float*)d_in[4];

    float* out = (float*)d_out;
    float* score_f = out;                        // [B,TQ,TK]
    float* ctx_f   = out + (size_t)BT;           // [B,TQ,DV]

    // Workspace (98 MB), stream-order aliasing:
    //   R1: q_f16 -> sc_f16 ; R2: k_f16 ; R3: qw_f16 -> vt_f16 ; R4: wt_f16
    char* ws = (char*)d_ws;
    f16* R1  = (f16*)ws;                   ws += (size_t)BT * 2;
    f16* R2  = (f16*)ws;                   ws += (size_t)BT * 2;
    f16* R3  = (f16*)ws;                   ws += (size_t)BT * 2;
    f16* wt  = (f16*)ws;                   ws += (size_t)MAT * 2;

    f16* qf = R1, *sc = R1;
    f16* kf = R2;
    f16* qw = R3, *vt = R3;

    dim3 blk(256);
    dim3 blk5(512);

    // casts (q + k in one launch) / W transpose
    cast2_f16<<<dim3((unsigned)(BT / 2048), 2), blk, 0, stream>>>(query, qf, keys, kf, BT);
    transpose64_f16<<<dim3(16, 16, 1), blk, 0, stream>>>(W, wt, D, D, 0, 0);

    // GEMM1: qW = query @ W  -> qw (fp16)
    gemm256<2, 0><<<dim3(4, 64, 1), blk5, 0, stream>>>(
        qf, wt, nullptr, qw, B * T, D, D, 0, 0, 0);

    // GEMM2 (+mask +softmax fused): score = softmax(qW @ keys^T + mask)
    gemm_softmax<<<dim3(1, 16, B), blk5, 0, stream>>>(
        qw, kf, mask, score_f, sc, T, D, MAT);

    // V^T fp16 (B operand of GEMM3) — after gemm_softmax so qw (R3) is dead
    transpose64_f16<<<dim3(16, 16, B), blk, 0, stream>>>(values, vt, T, D, MAT, MAT);

    // GEMM3: ctx = score @ values
    gemm256<0, 1><<<dim3(4, 4, B), blk5, 0, stream>>>(
        sc, vt, ctx_f, nullptr, T, D, T, MAT, MAT, MAT);
}